// Round 6
// baseline (584.514 us; speedup 1.0000x reference)
//
#include <hip/hip_runtime.h>
#include <hip/hip_bf16.h>
#include <cstdint>
#include <cstddef>
#include <cstring>

typedef unsigned short u16;
typedef unsigned char u8;
typedef __attribute__((ext_vector_type(8))) short short8;   // 8 x bf16 (4 VGPRs)
typedef __attribute__((ext_vector_type(4))) float f32x4;    // MFMA C/D

#define B_    4
#define T_    2048
#define D_    1024
#define H_    16
#define DK_   64
// SCALE * log2(e): scores exponentiate via 2^x (single v_exp_f32)
#define QSCALE_ 0.18033688011112042f

__device__ __forceinline__ float bf2f(u16 u) {
    unsigned int x = ((unsigned int)u) << 16;
    float f; __builtin_memcpy(&f, &x, 4); return f;
}
__device__ __forceinline__ u16 f2bf(float f) {
    unsigned int x; __builtin_memcpy(&x, &f, 4);
    x += 0x7fffu + ((x >> 16) & 1u);   // round-to-nearest-even
    return (u16)(x >> 16);
}

// ------------- Fused prep: dtype sniff + mask normalize + vec convert -------------
// One block; phases separated by syncthreads. flag: 1 = fp32 inputs.
__global__ __launch_bounds__(256) void prep_kernel(
    const u16* __restrict__ x, const u8* __restrict__ m,
    const void* s0, const void* s1, const void* s2, const void* s3,
    const void* s4, const void* s5,
    u16* __restrict__ vecs, u8* __restrict__ nm, int* flag, int n)
{
    __shared__ int tot, sbits;
    int tid = threadIdx.x;
    if (tid == 0) { tot = 0; sbits = 0; }
    __syncthreads();
    // dtype sniff: u16[2i] of x — bf16 data has sane exponents, fp32 low-mantissa
    // halves have uniform exponents (~84% extreme).
    int cnt = 0;
    for (int i = tid; i < 4096; i += 256) {
        int e = (x[2 * i] >> 7) & 0xFF;
        if (e > 137 || (e >= 1 && e < 97)) cnt++;
    }
    int bits = 0;
    for (int i = tid; i < n; i += 256)
        if (m[i]) bits |= (i & 7);
    for (int o = 1; o < 64; o <<= 1) { cnt += __shfl_xor(cnt, o); bits |= __shfl_xor(bits, o); }
    if ((tid & 63) == 0) { atomicAdd(&tot, cnt); if (bits) atomicOr(&sbits, bits); }
    __syncthreads();
    int f = (tot > 1024) ? 1 : 0;
    if (tid == 0) *flag = f;
    int b = sbits;
    int stride = (b & 1) ? 1 : (b & 2) ? 2 : (b & 4) ? 4 : 8;
    for (int i = tid; i < n; i += 256)
        nm[i] = m[(size_t)i * stride] ? 1 : 0;
    const void* ss[6] = {s0, s1, s2, s3, s4, s5};
    for (int t = 0; t < 6; t++) {
        const void* s = ss[t];
        for (int i = tid; i < 1024; i += 256)
            vecs[t * 1024 + i] = f ? f2bf(((const float*)s)[i]) : ((const u16*)s)[i];
    }
}

// ------------- Canonicalize 4 [1024,1024] weights to bf16 -------------
__global__ __launch_bounds__(256) void convert_w_kernel(
    const void* s0, const void* s1, const void* s2, const void* s3,
    u16* d0, u16* d1, u16* d2, u16* d3, const int* __restrict__ flag)
{
    const void* s; u16* d;
    if (blockIdx.y == 0)      { s = s0; d = d0; }
    else if (blockIdx.y == 1) { s = s1; d = d1; }
    else if (blockIdx.y == 2) { s = s2; d = d2; }
    else                      { s = s3; d = d3; }
    int i4 = blockIdx.x * 256 + threadIdx.x;     // quad index, 262144 total
    if (*flag) {
        float4 v = ((const float4*)s)[i4];
        ushort4 o; o.x = f2bf(v.x); o.y = f2bf(v.y); o.z = f2bf(v.z); o.w = f2bf(v.w);
        ((ushort4*)d)[i4] = o;
    } else {
        ((ushort4*)d)[i4] = ((const ushort4*)s)[i4];
    }
}

// ---------------- LayerNorm: [8192,1024] (fp32 or bf16) -> bf16 ----------------
__global__ __launch_bounds__(256) void ln_kernel(
    const void* __restrict__ x, const u16* __restrict__ g,
    const u16* __restrict__ be, u16* __restrict__ xn, const int* __restrict__ flag)
{
    int row = blockIdx.x;
    int t = threadIdx.x;
    float v[4];
    if (*flag) {
        float4 f4 = ((const float4*)x)[(size_t)row * 256 + t];
        v[0] = f4.x; v[1] = f4.y; v[2] = f4.z; v[3] = f4.w;
    } else {
        ushort4 uv = ((const ushort4*)x)[(size_t)row * 256 + t];
        v[0] = bf2f(uv.x); v[1] = bf2f(uv.y); v[2] = bf2f(uv.z); v[3] = bf2f(uv.w);
    }
    float s = v[0] + v[1] + v[2] + v[3];
    float q = v[0]*v[0] + v[1]*v[1] + v[2]*v[2] + v[3]*v[3];
    for (int o = 1; o < 64; o <<= 1) { s += __shfl_xor(s, o); q += __shfl_xor(q, o); }
    __shared__ float rs[4], rq[4];
    int wv = t >> 6, ln = t & 63;
    if (ln == 0) { rs[wv] = s; rq[wv] = q; }
    __syncthreads();
    s = rs[0] + rs[1] + rs[2] + rs[3];
    q = rq[0] + rq[1] + rq[2] + rq[3];
    float mu   = s * (1.0f / D_);
    float var  = q * (1.0f / D_) - mu * mu;
    float rstd = rsqrtf(var + 1e-5f);
    u16 o4[4];
    for (int i = 0; i < 4; i++) {
        float f = (v[i] - mu) * rstd * bf2f(g[t*4 + i]) + bf2f(be[t*4 + i]);
        o4[i] = f2bf(f);
    }
    ushort4 ov; ov.x = o4[0]; ov.y = o4[1]; ov.z = o4[2]; ov.w = o4[3];
    *(ushort4*)(xn + (size_t)row * D_ + t * 4) = ov;
}

// ------------- GEMM C = A[8192,1024] . W[1024,1024]^T + bias, *scale -------------
__global__ __launch_bounds__(256) void gemm_bt(
    const u16* __restrict__ A,
    const u16* __restrict__ W0, const u16* __restrict__ W1, const u16* __restrict__ W2,
    const u16* __restrict__ bias_all, int bias_idx0,
    u16* __restrict__ C0, u16* __restrict__ C1, u16* __restrict__ C2,
    float scale, const int* __restrict__ flag, int use_flag, int vt_mode)
{
    const int K = 1024, N = 1024;
    const u16* W; const u16* bias; u16* C;
    if (blockIdx.z == 0)      { W = W0; bias = bias_all + (size_t)bias_idx0 * 1024;       C = C0; }
    else if (blockIdx.z == 1) { W = W1; bias = bias_all + (size_t)(bias_idx0 + 1) * 1024; C = C1; }
    else                      { W = W2; bias = bias_all + (size_t)(bias_idx0 + 2) * 1024; C = C2; }

    __shared__ u16 As[128 * 32];   // no pad: required by global_load_lds layout
    __shared__ u16 Bs[128 * 32];

    int tid  = threadIdx.x;
    int wave = tid >> 6, lane = tid & 63;
    int wm = wave >> 1, wn = wave & 1;
    int quad = lane >> 4, l16 = lane & 15;
    int bm = blockIdx.y * 128, bn = blockIdx.x * 128;

    f32x4 acc[4][4];
    const f32x4 fz = {0.f, 0.f, 0.f, 0.f};
    for (int i = 0; i < 4; i++) for (int j = 0; j < 4; j++) acc[i][j] = fz;

    int srow = lane >> 2;
    int scol = (lane & 3) * 8;
    const u16* gA0 = A + (size_t)(bm + wave * 32 + srow) * K + scol;
    const u16* gB0 = W + (size_t)(bn + wave * 32 + srow) * K + scol;

    for (int k0 = 0; k0 < K; k0 += 32) {
        for (int i = 0; i < 2; i++) {
            __builtin_amdgcn_global_load_lds(
                (const __attribute__((address_space(1))) void*)(gA0 + (size_t)i * 16 * K + k0),
                (__attribute__((address_space(3))) void*)(As + (wave * 32 + i * 16) * 32),
                16, 0, 0);
            __builtin_amdgcn_global_load_lds(
                (const __attribute__((address_space(1))) void*)(gB0 + (size_t)i * 16 * K + k0),
                (__attribute__((address_space(3))) void*)(Bs + (wave * 32 + i * 16) * 32),
                16, 0, 0);
        }
        __syncthreads();
        short8 a[4], b[4];
        for (int i = 0; i < 4; i++)
            a[i] = *(const short8*)(As + (wm * 64 + i * 16 + l16) * 32 + quad * 8);
        for (int j = 0; j < 4; j++)
            b[j] = *(const short8*)(Bs + (wn * 64 + j * 16 + l16) * 32 + quad * 8);
        for (int i = 0; i < 4; i++)
            for (int j = 0; j < 4; j++)
                acc[i][j] = __builtin_amdgcn_mfma_f32_16x16x32_bf16(a[i], b[j], acc[i][j], 0, 0, 0);
        __syncthreads();
    }

    if (vt_mode && blockIdx.z == 2) {
        for (int j = 0; j < 4; j++) {
            int col = bn + wn * 64 + j * 16 + l16;
            int h = col >> 6, d = col & 63;
            float bi = bf2f(bias[col]);
            for (int i = 0; i < 4; i++) {
                int row0 = bm + wm * 64 + i * 16 + quad * 4;
                int bq = row0 >> 11, t0 = row0 & 2047;
                ushort4 pk;
                pk.x = f2bf(acc[i][j][0] + bi); pk.y = f2bf(acc[i][j][1] + bi);
                pk.z = f2bf(acc[i][j][2] + bi); pk.w = f2bf(acc[i][j][3] + bi);
                *(ushort4*)(C + ((size_t)((bq * 16 + h) * 64 + d)) * 2048 + t0) = pk;
            }
        }
        return;
    }

    int f32out = use_flag ? *flag : 0;
    for (int j = 0; j < 4; j++) {
        int col = bn + wn * 64 + j * 16 + l16;
        float bi = bf2f(bias[col]);
        for (int i = 0; i < 4; i++) {
            int row0 = bm + wm * 64 + i * 16 + quad * 4;
            for (int r = 0; r < 4; r++) {
                float o = (acc[i][j][r] + bi) * scale;
                if (f32out) ((float*)C)[(size_t)(row0 + r) * N + col] = o;
                else        C[(size_t)(row0 + r) * N + col] = f2bf(o);
            }
        }
    }
}

// ---------------- l2norm over 64-elem head chunks (K only), in place ----------------
__global__ __launch_bounds__(256) void l2norm_kernel(u16* __restrict__ P)
{
    int wave = threadIdx.x >> 6, lane = threadIdx.x & 63;
    size_t off = ((size_t)blockIdx.x * 4 + wave) * 64 + lane;
    float v = bf2f(P[off]);
    float q = v * v;
    for (int o = 1; o < 64; o <<= 1) q += __shfl_xor(q, o);
    float n = fmaxf(sqrtf(q), 1e-8f);
    P[off] = f2bf(v / n);
}

// ---------------- Flash-style attention v4 ----------------
// 128 queries/block (32/wave). S^T trick (mfma(K,Q) -> packed Ps row stores).
// Q l2norm + QSCALE folded in-register. Single-buffer K/Vt staging w/ register
// prefetch, 2 barriers/tile; 36.8 KB LDS -> 4 blocks/CU (16 waves).
__global__ __launch_bounds__(256, 4) void attn_kernel(
    const u16* __restrict__ Q, const u16* __restrict__ Kg,
    const u16* __restrict__ Vt, const u8* __restrict__ nm,
    u16* __restrict__ Oout)
{
    __shared__ u16 Ks[64 * 72];      // [key][dk]
    __shared__ u16 VTs[64 * 72];     // [dk][key]
    __shared__ u16 Ps[128 * 72];     // [query][key] (wave-private row blocks)
    __shared__ __align__(16) float msf[64];  // mask multiplier per key
    __shared__ float l_sh[128];      // per-query denominators

    int tid  = threadIdx.x;
    int wave = tid >> 6, lane = tid & 63;
    int quad = lane >> 4, l16 = lane & 15;
    int q0 = blockIdx.x * 128;
    int b  = blockIdx.y >> 4, h = blockIdx.y & 15;
    const size_t base  = (size_t)b * T_ * D_ + h * DK_;
    const size_t vbase = (size_t)((b * 16 + h) * 64) * T_;

    // Q fragments for two 16-query groups; l2norm + QSCALE folded in-register.
    short8 qa[2][2];
    for (int g = 0; g < 2; g++) {
        const u16* qrow = Q + base + (size_t)(q0 + wave * 32 + g * 16 + l16) * D_;
        qa[g][0] = *(const short8*)(qrow + quad * 8);
        qa[g][1] = *(const short8*)(qrow + 32 + quad * 8);
        float s = 0.f;
        for (int hh = 0; hh < 2; hh++) {
            const u16* e = (const u16*)&qa[g][hh];
            for (int k = 0; k < 8; k++) { float v = bf2f(e[k]); s += v * v; }
        }
        s += __shfl_xor(s, 16); s += __shfl_xor(s, 32);
        float scg = QSCALE_ / fmaxf(sqrtf(s), 1e-8f);
        for (int hh = 0; hh < 2; hh++) {
            u16* e = (u16*)&qa[g][hh];
            for (int k = 0; k < 8; k++) e[k] = f2bf(bf2f(e[k]) * scg);
        }
    }

    int sr = tid >> 3;                 // 0..31 (p adds 32)
    int sc = (tid & 7) * 8;
    const u8* mrow = nm + b * T_;

    // prologue: stage tile 0
    for (int p = 0; p < 2; p++) {
        int r = sr + p * 32;
        *(short8*)(&Ks[r * 72 + sc])  = *(const short8*)(Kg + base + (size_t)r * D_ + sc);
        *(short8*)(&VTs[r * 72 + sc]) = *(const short8*)(Vt + vbase + (size_t)r * T_ + sc);
    }
    if (tid < 64) msf[tid] = mrow[tid] ? 0.f : 1.f;
    __syncthreads();

    const f32x4 fz = {0.f, 0.f, 0.f, 0.f};
    f32x4 o_acc[2][4];
    for (int g = 0; g < 2; g++) for (int j = 0; j < 4; j++) o_acc[g][j] = fz;
    float rowsum[2] = {0.f, 0.f};

    for (int kt = 0; kt < T_; kt += 64) {
        int ktn = (kt + 64) & (T_ - 1);
        // prefetch next tile into registers (written to LDS after barrier)
        short8 kpre[2], vpre[2];
        for (int p = 0; p < 2; p++) {
            int r = sr + p * 32;
            kpre[p] = *(const short8*)(Kg + base + (size_t)(ktn + r) * D_ + sc);
            vpre[p] = *(const short8*)(Vt + vbase + (size_t)r * T_ + ktn + sc);
        }
        u8 mpre = (tid < 64) ? mrow[ktn + tid] : (u8)0;

        // ---- S^T = K.Q^T -> exp2 -> mask-mul -> packed Ps stores ----
        for (int j = 0; j < 4; j++) {
            short8 kb0 = *(const short8*)(Ks + (j * 16 + l16) * 72 + quad * 8);
            short8 kb1 = *(const short8*)(Ks + (j * 16 + l16) * 72 + 32 + quad * 8);
            f32x4 s4[2];
            for (int g = 0; g < 2; g++) {
                f32x4 t = __builtin_amdgcn_mfma_f32_16x16x32_bf16(kb0, qa[g][0], fz, 0, 0, 0);
                s4[g]   = __builtin_amdgcn_mfma_f32_16x16x32_bf16(kb1, qa[g][1], t, 0, 0, 0);
            }
            f32x4 pm4 = *(const f32x4*)&msf[j * 16 + quad * 4];
            for (int g = 0; g < 2; g++) {
                float p0 = __builtin_exp2f(s4[g][0]) * pm4[0];
                float p1 = __builtin_exp2f(s4[g][1]) * pm4[1];
                float p2 = __builtin_exp2f(s4[g][2]) * pm4[2];
                float p3 = __builtin_exp2f(s4[g][3]) * pm4[3];
                rowsum[g] += (p0 + p1) + (p2 + p3);
                __hip_bfloat162 h01 = __float22bfloat162_rn(float2{p0, p1});
                __hip_bfloat162 h23 = __float22bfloat162_rn(float2{p2, p3});
                uint2 pk;
                __builtin_memcpy(&pk.x, &h01, 4);
                __builtin_memcpy(&pk.y, &h23, 4);
                *(uint2*)(Ps + (wave * 32 + g * 16 + l16) * 72 + j * 16 + quad * 4) = pk;
            }
        }

        // ---- O += P.V (own Ps rows; in-wave DS ordering suffices) ----
        short8 pa0[2], pa1[2];
        for (int g = 0; g < 2; g++) {
            pa0[g] = *(const short8*)(Ps + (wave * 32 + g * 16 + l16) * 72 + quad * 8);
            pa1[g] = *(const short8*)(Ps + (wave * 32 + g * 16 + l16) * 72 + 32 + quad * 8);
        }
        for (int j = 0; j < 4; j++) {
            short8 vb0 = *(const short8*)(VTs + (j * 16 + l16) * 72 + quad * 8);
            short8 vb1 = *(const short8*)(VTs + (j * 16 + l16) * 72 + 32 + quad * 8);
            for (int g = 0; g < 2; g++) {
                o_acc[g][j] = __builtin_amdgcn_mfma_f32_16x16x32_bf16(pa0[g], vb0, o_acc[g][j], 0, 0, 0);
                o_acc[g][j] = __builtin_amdgcn_mfma_f32_16x16x32_bf16(pa1[g], vb1, o_acc[g][j], 0, 0, 0);
            }
        }

        __syncthreads();   // everyone done reading Ks/VTs/msf
        for (int p = 0; p < 2; p++) {
            int r = sr + p * 32;
            *(short8*)(&Ks[r * 72 + sc])  = kpre[p];
            *(short8*)(&VTs[r * 72 + sc]) = vpre[p];
        }
        if (tid < 64) msf[tid] = mpre ? 0.f : 1.f;
        __syncthreads();   // writes visible
    }

    // denominators: reduce across quads (lanes l16 + 16q)
    for (int g = 0; g < 2; g++) {
        float l = rowsum[g];
        l += __shfl_xor(l, 16);
        l += __shfl_xor(l, 32);
        if (quad == 0) l_sh[wave * 32 + g * 16 + l16] = l;  // own-wave region
    }

    for (int g = 0; g < 2; g++) {
        for (int j = 0; j < 4; j++) {
            for (int r = 0; r < 4; r++) {
                int row = wave * 32 + g * 16 + quad * 4 + r;
                float ld = fmaxf(l_sh[row], 1e-20f);
                float o = o_acc[g][j][r] / ld;
                Oout[base + (size_t)(q0 + row) * D_ + j * 16 + l16] = f2bf(o);
            }
        }
    }
}

extern "C" void kernel_launch(void* const* d_in, const int* in_sizes, int n_in,
                              void* d_out, int out_size, void* d_ws, size_t ws_size,
                              hipStream_t stream)
{
    const void* x    = d_in[0];
    const u8*   mask = (const u8*)d_in[1];
    const void* wq   = d_in[2];
    const void* bq   = d_in[3];
    const void* wk   = d_in[4];
    const void* bk   = d_in[5];
    const void* wv   = d_in[6];
    const void* bv   = d_in[7];
    const void* wo   = d_in[8];
    const void* bo   = d_in[9];
    const void* lng  = d_in[10];
    const void* lnb  = d_in[11];

    const size_t NTOK = (size_t)B_ * T_;          // 8192
    u16* xn  = (u16*)d_ws;                        // 16.8 MB; reused as attention output
    u16* Kb  = xn + NTOK * D_;                    // 16.8 MB
    u16* Vtb = Kb + NTOK * D_;                    // 16.8 MB (transposed layout)
    u16* wqc = Vtb + NTOK * D_;                   // 2 MB each
    u16* wkc = wqc + (size_t)D_ * D_;
    u16* wvc = wkc + (size_t)D_ * D_;
    u16* woc = wvc + (size_t)D_ * D_;
    u16* vecs = woc + (size_t)D_ * D_;            // 6 x 1024: bq,bk,bv,bo,ln_g,ln_b
    u8*  nm  = (u8*)(vecs + 6 * 1024);            // 8 KB canonical mask
    int* flag = (int*)(nm + 8192);                // dtype flag: 1 = fp32 inputs
    u16* Qb  = (u16*)d_out;                       // Q in d_out (dead until final GEMM)

    prep_kernel<<<dim3(1), 256, 0, stream>>>((const u16*)x, mask, bq, bk, bv, bo, lng, lnb,
                                             vecs, nm, flag, B_ * T_);
    convert_w_kernel<<<dim3(1024, 4), 256, 0, stream>>>(wq, wk, wv, wo, wqc, wkc, wvc, woc, flag);
    ln_kernel<<<dim3(NTOK), 256, 0, stream>>>(x, vecs + 4 * 1024, vecs + 5 * 1024, xn, flag);
    gemm_bt<<<dim3(8, 64, 3), 256, 0, stream>>>(xn, wqc, wkc, wvc, vecs, 0, Qb, Kb, Vtb, 1.0f, flag, 0, 1);
    l2norm_kernel<<<dim3(32768), 256, 0, stream>>>(Kb);
    attn_kernel<<<dim3(16, 64), 256, 0, stream>>>(Qb, Kb, Vtb, nm, xn);
    gemm_bt<<<dim3(8, 64, 1), 256, 0, stream>>>(xn, woc, woc, woc, vecs, 3, (u16*)d_out, (u16*)d_out, (u16*)d_out, 0.5f, flag, 1, 0);
}

// Round 7
// 420.813 us; speedup vs baseline: 1.3890x; 1.3890x over previous
//
#include <hip/hip_runtime.h>
#include <hip/hip_bf16.h>
#include <cstdint>
#include <cstddef>
#include <cstring>

typedef unsigned short u16;
typedef unsigned char u8;
typedef __attribute__((ext_vector_type(8))) short short8;   // 8 x bf16 (4 VGPRs)
typedef __attribute__((ext_vector_type(4))) float f32x4;    // MFMA C/D

#define B_    4
#define T_    2048
#define D_    1024
#define H_    16
#define DK_   64
// SCALE * log2(e): scores exponentiate via 2^x (single v_exp_f32)
#define QSCALE_ 0.18033688011112042f

__device__ __forceinline__ float bf2f(u16 u) {
    unsigned int x = ((unsigned int)u) << 16;
    float f; __builtin_memcpy(&f, &x, 4); return f;
}
__device__ __forceinline__ u16 f2bf(float f) {
    unsigned int x; __builtin_memcpy(&x, &f, 4);
    x += 0x7fffu + ((x >> 16) & 1u);   // round-to-nearest-even
    return (u16)(x >> 16);
}

// ------------- Fused prep: dtype sniff + mask normalize + vec convert -------------
__global__ __launch_bounds__(256) void prep_kernel(
    const u16* __restrict__ x, const u8* __restrict__ m,
    const void* s0, const void* s1, const void* s2, const void* s3,
    const void* s4, const void* s5,
    u16* __restrict__ vecs, u8* __restrict__ nm, int* flag, int n)
{
    __shared__ int tot, sbits;
    int tid = threadIdx.x;
    if (tid == 0) { tot = 0; sbits = 0; }
    __syncthreads();
    int cnt = 0;
    for (int i = tid; i < 4096; i += 256) {
        int e = (x[2 * i] >> 7) & 0xFF;
        if (e > 137 || (e >= 1 && e < 97)) cnt++;
    }
    int bits = 0;
    for (int i = tid; i < n; i += 256)
        if (m[i]) bits |= (i & 7);
    for (int o = 1; o < 64; o <<= 1) { cnt += __shfl_xor(cnt, o); bits |= __shfl_xor(bits, o); }
    if ((tid & 63) == 0) { atomicAdd(&tot, cnt); if (bits) atomicOr(&sbits, bits); }
    __syncthreads();
    int f = (tot > 1024) ? 1 : 0;
    if (tid == 0) *flag = f;
    int b = sbits;
    int stride = (b & 1) ? 1 : (b & 2) ? 2 : (b & 4) ? 4 : 8;
    for (int i = tid; i < n; i += 256)
        nm[i] = m[(size_t)i * stride] ? 1 : 0;
    const void* ss[6] = {s0, s1, s2, s3, s4, s5};
    for (int t = 0; t < 6; t++) {
        const void* s = ss[t];
        for (int i = tid; i < 1024; i += 256)
            vecs[t * 1024 + i] = f ? f2bf(((const float*)s)[i]) : ((const u16*)s)[i];
    }
}

// ------------- Canonicalize 4 [1024,1024] weights to bf16 -------------
__global__ __launch_bounds__(256) void convert_w_kernel(
    const void* s0, const void* s1, const void* s2, const void* s3,
    u16* d0, u16* d1, u16* d2, u16* d3, const int* __restrict__ flag)
{
    const void* s; u16* d;
    if (blockIdx.y == 0)      { s = s0; d = d0; }
    else if (blockIdx.y == 1) { s = s1; d = d1; }
    else if (blockIdx.y == 2) { s = s2; d = d2; }
    else                      { s = s3; d = d3; }
    int i4 = blockIdx.x * 256 + threadIdx.x;     // quad index, 262144 total
    if (*flag) {
        float4 v = ((const float4*)s)[i4];
        ushort4 o; o.x = f2bf(v.x); o.y = f2bf(v.y); o.z = f2bf(v.z); o.w = f2bf(v.w);
        ((ushort4*)d)[i4] = o;
    } else {
        ((ushort4*)d)[i4] = ((const ushort4*)s)[i4];
    }
}

// ---------------- LayerNorm: [8192,1024] (fp32 or bf16) -> bf16 ----------------
__global__ __launch_bounds__(256) void ln_kernel(
    const void* __restrict__ x, const u16* __restrict__ g,
    const u16* __restrict__ be, u16* __restrict__ xn, const int* __restrict__ flag)
{
    int row = blockIdx.x;
    int t = threadIdx.x;
    float v[4];
    if (*flag) {
        float4 f4 = ((const float4*)x)[(size_t)row * 256 + t];
        v[0] = f4.x; v[1] = f4.y; v[2] = f4.z; v[3] = f4.w;
    } else {
        ushort4 uv = ((const ushort4*)x)[(size_t)row * 256 + t];
        v[0] = bf2f(uv.x); v[1] = bf2f(uv.y); v[2] = bf2f(uv.z); v[3] = bf2f(uv.w);
    }
    float s = v[0] + v[1] + v[2] + v[3];
    float q = v[0]*v[0] + v[1]*v[1] + v[2]*v[2] + v[3]*v[3];
    for (int o = 1; o < 64; o <<= 1) { s += __shfl_xor(s, o); q += __shfl_xor(q, o); }
    __shared__ float rs[4], rq[4];
    int wv = t >> 6, ln = t & 63;
    if (ln == 0) { rs[wv] = s; rq[wv] = q; }
    __syncthreads();
    s = rs[0] + rs[1] + rs[2] + rs[3];
    q = rq[0] + rq[1] + rq[2] + rq[3];
    float mu   = s * (1.0f / D_);
    float var  = q * (1.0f / D_) - mu * mu;
    float rstd = rsqrtf(var + 1e-5f);
    u16 o4[4];
    for (int i = 0; i < 4; i++) {
        float f = (v[i] - mu) * rstd * bf2f(g[t*4 + i]) + bf2f(be[t*4 + i]);
        o4[i] = f2bf(f);
    }
    ushort4 ov; ov.x = o4[0]; ov.y = o4[1]; ov.z = o4[2]; ov.w = o4[3];
    *(ushort4*)(xn + (size_t)row * D_ + t * 4) = ov;
}

// ------------- GEMM C = A[8192,1024] . W[1024,1024]^T + bias, *scale -------------
__global__ __launch_bounds__(256) void gemm_bt(
    const u16* __restrict__ A,
    const u16* __restrict__ W0, const u16* __restrict__ W1, const u16* __restrict__ W2,
    const u16* __restrict__ bias_all, int bias_idx0,
    u16* __restrict__ C0, u16* __restrict__ C1, u16* __restrict__ C2,
    float scale, const int* __restrict__ flag, int use_flag, int vt_mode)
{
    const int K = 1024, N = 1024;
    const u16* W; const u16* bias; u16* C;
    if (blockIdx.z == 0)      { W = W0; bias = bias_all + (size_t)bias_idx0 * 1024;       C = C0; }
    else if (blockIdx.z == 1) { W = W1; bias = bias_all + (size_t)(bias_idx0 + 1) * 1024; C = C1; }
    else                      { W = W2; bias = bias_all + (size_t)(bias_idx0 + 2) * 1024; C = C2; }

    __shared__ u16 As[128 * 32];   // no pad: required by global_load_lds layout
    __shared__ u16 Bs[128 * 32];

    int tid  = threadIdx.x;
    int wave = tid >> 6, lane = tid & 63;
    int wm = wave >> 1, wn = wave & 1;
    int quad = lane >> 4, l16 = lane & 15;
    int bm = blockIdx.y * 128, bn = blockIdx.x * 128;

    f32x4 acc[4][4];
    const f32x4 fz = {0.f, 0.f, 0.f, 0.f};
    for (int i = 0; i < 4; i++) for (int j = 0; j < 4; j++) acc[i][j] = fz;

    int srow = lane >> 2;
    int scol = (lane & 3) * 8;
    const u16* gA0 = A + (size_t)(bm + wave * 32 + srow) * K + scol;
    const u16* gB0 = W + (size_t)(bn + wave * 32 + srow) * K + scol;

    for (int k0 = 0; k0 < K; k0 += 32) {
        for (int i = 0; i < 2; i++) {
            __builtin_amdgcn_global_load_lds(
                (const __attribute__((address_space(1))) void*)(gA0 + (size_t)i * 16 * K + k0),
                (__attribute__((address_space(3))) void*)(As + (wave * 32 + i * 16) * 32),
                16, 0, 0);
            __builtin_amdgcn_global_load_lds(
                (const __attribute__((address_space(1))) void*)(gB0 + (size_t)i * 16 * K + k0),
                (__attribute__((address_space(3))) void*)(Bs + (wave * 32 + i * 16) * 32),
                16, 0, 0);
        }
        __syncthreads();
        short8 a[4], b[4];
        for (int i = 0; i < 4; i++)
            a[i] = *(const short8*)(As + (wm * 64 + i * 16 + l16) * 32 + quad * 8);
        for (int j = 0; j < 4; j++)
            b[j] = *(const short8*)(Bs + (wn * 64 + j * 16 + l16) * 32 + quad * 8);
        for (int i = 0; i < 4; i++)
            for (int j = 0; j < 4; j++)
                acc[i][j] = __builtin_amdgcn_mfma_f32_16x16x32_bf16(a[i], b[j], acc[i][j], 0, 0, 0);
        __syncthreads();
    }

    if (vt_mode && blockIdx.z == 2) {
        for (int j = 0; j < 4; j++) {
            int col = bn + wn * 64 + j * 16 + l16;
            int h = col >> 6, d = col & 63;
            float bi = bf2f(bias[col]);
            for (int i = 0; i < 4; i++) {
                int row0 = bm + wm * 64 + i * 16 + quad * 4;
                int bq = row0 >> 11, t0 = row0 & 2047;
                ushort4 pk;
                pk.x = f2bf(acc[i][j][0] + bi); pk.y = f2bf(acc[i][j][1] + bi);
                pk.z = f2bf(acc[i][j][2] + bi); pk.w = f2bf(acc[i][j][3] + bi);
                *(ushort4*)(C + ((size_t)((bq * 16 + h) * 64 + d)) * 2048 + t0) = pk;
            }
        }
        return;
    }

    int f32out = use_flag ? *flag : 0;
    for (int j = 0; j < 4; j++) {
        int col = bn + wn * 64 + j * 16 + l16;
        float bi = bf2f(bias[col]);
        for (int i = 0; i < 4; i++) {
            int row0 = bm + wm * 64 + i * 16 + quad * 4;
            for (int r = 0; r < 4; r++) {
                float o = (acc[i][j][r] + bi) * scale;
                if (f32out) ((float*)C)[(size_t)(row0 + r) * N + col] = o;
                else        C[(size_t)(row0 + r) * N + col] = f2bf(o);
            }
        }
    }
}

// ---------------- l2norm over 64-elem head chunks, in place ----------------
// Q branch folds SCALE*log2(e) so attention exponentiates via 2^x.
__global__ __launch_bounds__(256) void l2norm_kernel(u16* __restrict__ Q, u16* __restrict__ Kk)
{
    u16* P = blockIdx.y ? Kk : Q;
    float sc = blockIdx.y ? 1.0f : QSCALE_;
    int wave = threadIdx.x >> 6, lane = threadIdx.x & 63;
    size_t off = ((size_t)blockIdx.x * 4 + wave) * 64 + lane;
    float v = bf2f(P[off]);
    float q = v * v;
    for (int o = 1; o < 64; o <<= 1) q += __shfl_xor(q, o);
    float n = fmaxf(sqrtf(q), 1e-8f);
    P[off] = f2bf(v / n * sc);
}

// ---------------- Flash-style attention v5 (= v3 dataflow, single-buffer) ----------------
// v3's 64-query S^T kernel (68 VGPR, no spills) with single-buffered K/Vt:
// LDS 47->28 KB => 5 blocks/CU (20 waves). Register prefetch covers global
// latency; 2 barriers/tile amortized across 5 independent blocks.
__global__ __launch_bounds__(256, 4) void attn_kernel(
    const u16* __restrict__ Q, const u16* __restrict__ Kg,
    const u16* __restrict__ Vt, const u8* __restrict__ nm,
    u16* __restrict__ Oout)
{
    __shared__ u16 Ks[64 * 72];      // [key][dk]
    __shared__ u16 VTs[64 * 72];     // [dk][key]
    __shared__ u16 Ps[64 * 72];      // [query][key] (wave-private row blocks)
    __shared__ __align__(16) float msf[64];  // mask multiplier per key
    __shared__ float l_sh[64];       // per-query denominators

    int tid  = threadIdx.x;
    int wave = tid >> 6, lane = tid & 63;
    int quad = lane >> 4, l16 = lane & 15;
    int q0 = blockIdx.x * 64;
    int b  = blockIdx.y >> 4, h = blockIdx.y & 15;
    const size_t base  = (size_t)b * T_ * D_ + h * DK_;
    const size_t vbase = (size_t)((b * 16 + h) * 64) * T_;

    // Q fragments: direct global->register, once per block (used as B operand)
    const u16* qrow = Q + base + (size_t)(q0 + wave * 16 + l16) * D_;
    short8 qa0 = *(const short8*)(qrow + quad * 8);
    short8 qa1 = *(const short8*)(qrow + 32 + quad * 8);

    int sr = tid >> 3;                 // 0..31 (p adds 32)
    int sc = (tid & 7) * 8;
    const u8* mrow = nm + b * T_;

    // prologue: stage tile 0
    for (int p = 0; p < 2; p++) {
        int r = sr + p * 32;
        *(short8*)(&Ks[r * 72 + sc])  = *(const short8*)(Kg + base + (size_t)r * D_ + sc);
        *(short8*)(&VTs[r * 72 + sc]) = *(const short8*)(Vt + vbase + (size_t)r * T_ + sc);
    }
    if (tid < 64) msf[tid] = mrow[tid] ? 0.f : 1.f;
    __syncthreads();

    const f32x4 fz = {0.f, 0.f, 0.f, 0.f};
    f32x4 o_acc[4];
    for (int j = 0; j < 4; j++) o_acc[j] = fz;
    float rowsum = 0.f;   // partial denominator for query=l16 (this lane's keys)

    for (int kt = 0; kt < T_; kt += 64) {
        int ktn = (kt + 64) & (T_ - 1);
        // prefetch next tile into registers (written to LDS after barrier)
        short8 kpre[2], vpre[2];
        for (int p = 0; p < 2; p++) {
            int r = sr + p * 32;
            kpre[p] = *(const short8*)(Kg + base + (size_t)(ktn + r) * D_ + sc);
            vpre[p] = *(const short8*)(Vt + vbase + (size_t)r * T_ + ktn + sc);
        }
        u8 mpre = (tid < 64) ? mrow[ktn + tid] : (u8)0;

        // ---- S^T = K.Q^T -> exp2 -> mask-mul -> packed Ps store ----
        for (int j = 0; j < 4; j++) {
            short8 kb0 = *(const short8*)(Ks + (j * 16 + l16) * 72 + quad * 8);
            short8 kb1 = *(const short8*)(Ks + (j * 16 + l16) * 72 + 32 + quad * 8);
            f32x4 s4 = __builtin_amdgcn_mfma_f32_16x16x32_bf16(kb0, qa0, fz, 0, 0, 0);
            s4       = __builtin_amdgcn_mfma_f32_16x16x32_bf16(kb1, qa1, s4, 0, 0, 0);
            f32x4 pm4 = *(const f32x4*)&msf[j * 16 + quad * 4];
            float p0 = __builtin_exp2f(s4[0]) * pm4[0];
            float p1 = __builtin_exp2f(s4[1]) * pm4[1];
            float p2 = __builtin_exp2f(s4[2]) * pm4[2];
            float p3 = __builtin_exp2f(s4[3]) * pm4[3];
            rowsum += (p0 + p1) + (p2 + p3);
            __hip_bfloat162 h01 = __float22bfloat162_rn(float2{p0, p1});
            __hip_bfloat162 h23 = __float22bfloat162_rn(float2{p2, p3});
            uint2 pk;
            __builtin_memcpy(&pk.x, &h01, 4);
            __builtin_memcpy(&pk.y, &h23, 4);
            *(uint2*)(Ps + (wave * 16 + l16) * 72 + j * 16 + quad * 4) = pk;
        }

        // ---- O += P.V (own Ps rows; in-wave DS ordering suffices) ----
        short8 pa0 = *(const short8*)(Ps + (wave * 16 + l16) * 72 + quad * 8);
        short8 pa1 = *(const short8*)(Ps + (wave * 16 + l16) * 72 + 32 + quad * 8);
        for (int j = 0; j < 4; j++) {
            short8 vb0 = *(const short8*)(VTs + (j * 16 + l16) * 72 + quad * 8);
            short8 vb1 = *(const short8*)(VTs + (j * 16 + l16) * 72 + 32 + quad * 8);
            o_acc[j] = __builtin_amdgcn_mfma_f32_16x16x32_bf16(pa0, vb0, o_acc[j], 0, 0, 0);
            o_acc[j] = __builtin_amdgcn_mfma_f32_16x16x32_bf16(pa1, vb1, o_acc[j], 0, 0, 0);
        }

        __syncthreads();   // everyone done reading Ks/VTs/msf
        for (int p = 0; p < 2; p++) {
            int r = sr + p * 32;
            *(short8*)(&Ks[r * 72 + sc])  = kpre[p];
            *(short8*)(&VTs[r * 72 + sc]) = vpre[p];
        }
        if (tid < 64) msf[tid] = mpre ? 0.f : 1.f;
        __syncthreads();   // writes visible
    }

    // reduce rowsum across quads (lanes l16, +16, +32, +48) -> denominator
    float l = rowsum;
    l += __shfl_xor(l, 16);
    l += __shfl_xor(l, 32);
    if (quad == 0) l_sh[wave * 16 + l16] = l;   // own-wave region; DS-ordered

    for (int j = 0; j < 4; j++) {
        for (int r = 0; r < 4; r++) {
            int row = wave * 16 + quad * 4 + r;
            float ld = fmaxf(l_sh[row], 1e-20f);
            float o = o_acc[j][r] / ld;
            Oout[base + (size_t)(q0 + row) * D_ + j * 16 + l16] = f2bf(o);
        }
    }
}

extern "C" void kernel_launch(void* const* d_in, const int* in_sizes, int n_in,
                              void* d_out, int out_size, void* d_ws, size_t ws_size,
                              hipStream_t stream)
{
    const void* x    = d_in[0];
    const u8*   mask = (const u8*)d_in[1];
    const void* wq   = d_in[2];
    const void* bq   = d_in[3];
    const void* wk   = d_in[4];
    const void* bk   = d_in[5];
    const void* wv   = d_in[6];
    const void* bv   = d_in[7];
    const void* wo   = d_in[8];
    const void* bo   = d_in[9];
    const void* lng  = d_in[10];
    const void* lnb  = d_in[11];

    const size_t NTOK = (size_t)B_ * T_;          // 8192
    u16* xn  = (u16*)d_ws;                        // 16.8 MB; reused as attention output
    u16* Kb  = xn + NTOK * D_;                    // 16.8 MB
    u16* Vtb = Kb + NTOK * D_;                    // 16.8 MB (transposed layout)
    u16* wqc = Vtb + NTOK * D_;                   // 2 MB each
    u16* wkc = wqc + (size_t)D_ * D_;
    u16* wvc = wkc + (size_t)D_ * D_;
    u16* woc = wvc + (size_t)D_ * D_;
    u16* vecs = woc + (size_t)D_ * D_;            // 6 x 1024: bq,bk,bv,bo,ln_g,ln_b
    u8*  nm  = (u8*)(vecs + 6 * 1024);            // 8 KB canonical mask
    int* flag = (int*)(nm + 8192);                // dtype flag: 1 = fp32 inputs
    u16* Qb  = (u16*)d_out;                       // Q in d_out (dead until final GEMM)

    prep_kernel<<<dim3(1), 256, 0, stream>>>((const u16*)x, mask, bq, bk, bv, bo, lng, lnb,
                                             vecs, nm, flag, B_ * T_);
    convert_w_kernel<<<dim3(1024, 4), 256, 0, stream>>>(wq, wk, wv, wo, wqc, wkc, wvc, woc, flag);
    ln_kernel<<<dim3(NTOK), 256, 0, stream>>>(x, vecs + 4 * 1024, vecs + 5 * 1024, xn, flag);
    gemm_bt<<<dim3(8, 64, 3), 256, 0, stream>>>(xn, wqc, wkc, wvc, vecs, 0, Qb, Kb, Vtb, 1.0f, flag, 0, 1);
    l2norm_kernel<<<dim3(32768, 2), 256, 0, stream>>>(Qb, Kb);
    attn_kernel<<<dim3(32, 64), 256, 0, stream>>>(Qb, Kb, Vtb, nm, xn);
    gemm_bt<<<dim3(8, 64, 1), 256, 0, stream>>>(xn, woc, woc, woc, vecs, 3, (u16*)d_out, (u16*)d_out, (u16*)d_out, 0.5f, flag, 1, 0);
}

// Round 8
// 381.665 us; speedup vs baseline: 1.5315x; 1.1026x over previous
//
#include <hip/hip_runtime.h>
#include <hip/hip_bf16.h>
#include <cstdint>
#include <cstddef>
#include <cstring>

typedef unsigned short u16;
typedef unsigned char u8;
typedef __attribute__((ext_vector_type(8))) short short8;   // 8 x bf16 (4 VGPRs)
typedef __attribute__((ext_vector_type(4))) float f32x4;    // MFMA C/D

#define B_    4
#define T_    2048
#define D_    1024
#define H_    16
#define DK_   64
// SCALE * log2(e): scores exponentiate via 2^x (single v_exp_f32)
#define QSCALE_ 0.18033688011112042f

__device__ __forceinline__ float bf2f(u16 u) {
    unsigned int x = ((unsigned int)u) << 16;
    float f; __builtin_memcpy(&f, &x, 4); return f;
}
__device__ __forceinline__ u16 f2bf(float f) {
    unsigned int x; __builtin_memcpy(&x, &f, 4);
    x += 0x7fffu + ((x >> 16) & 1u);   // round-to-nearest-even
    return (u16)(x >> 16);
}

// ------------- Fused prep: dtype sniff + mask normalize + vec convert -------------
__global__ __launch_bounds__(256) void prep_kernel(
    const u16* __restrict__ x, const u8* __restrict__ m,
    const void* s0, const void* s1, const void* s2, const void* s3,
    const void* s4, const void* s5,
    u16* __restrict__ vecs, u8* __restrict__ nm, int* flag, int n)
{
    __shared__ int tot, sbits;
    int tid = threadIdx.x;
    if (tid == 0) { tot = 0; sbits = 0; }
    __syncthreads();
    int cnt = 0;
    for (int i = tid; i < 4096; i += 256) {
        int e = (x[2 * i] >> 7) & 0xFF;
        if (e > 137 || (e >= 1 && e < 97)) cnt++;
    }
    int bits = 0;
    for (int i = tid; i < n; i += 256)
        if (m[i]) bits |= (i & 7);
    for (int o = 1; o < 64; o <<= 1) { cnt += __shfl_xor(cnt, o); bits |= __shfl_xor(bits, o); }
    if ((tid & 63) == 0) { atomicAdd(&tot, cnt); if (bits) atomicOr(&sbits, bits); }
    __syncthreads();
    int f = (tot > 1024) ? 1 : 0;
    if (tid == 0) *flag = f;
    int b = sbits;
    int stride = (b & 1) ? 1 : (b & 2) ? 2 : (b & 4) ? 4 : 8;
    for (int i = tid; i < n; i += 256)
        nm[i] = m[(size_t)i * stride] ? 1 : 0;
    const void* ss[6] = {s0, s1, s2, s3, s4, s5};
    for (int t = 0; t < 6; t++) {
        const void* s = ss[t];
        for (int i = tid; i < 1024; i += 256)
            vecs[t * 1024 + i] = f ? f2bf(((const float*)s)[i]) : ((const u16*)s)[i];
    }
}

// ------------- Canonicalize 4 [1024,1024] weights to bf16 -------------
__global__ __launch_bounds__(256) void convert_w_kernel(
    const void* s0, const void* s1, const void* s2, const void* s3,
    u16* d0, u16* d1, u16* d2, u16* d3, const int* __restrict__ flag)
{
    const void* s; u16* d;
    if (blockIdx.y == 0)      { s = s0; d = d0; }
    else if (blockIdx.y == 1) { s = s1; d = d1; }
    else if (blockIdx.y == 2) { s = s2; d = d2; }
    else                      { s = s3; d = d3; }
    int i4 = blockIdx.x * 256 + threadIdx.x;     // quad index, 262144 total
    if (*flag) {
        float4 v = ((const float4*)s)[i4];
        ushort4 o; o.x = f2bf(v.x); o.y = f2bf(v.y); o.z = f2bf(v.z); o.w = f2bf(v.w);
        ((ushort4*)d)[i4] = o;
    } else {
        ((ushort4*)d)[i4] = ((const ushort4*)s)[i4];
    }
}

// ---------------- LayerNorm: [8192,1024] (fp32 or bf16) -> bf16 ----------------
__global__ __launch_bounds__(256) void ln_kernel(
    const void* __restrict__ x, const u16* __restrict__ g,
    const u16* __restrict__ be, u16* __restrict__ xn, const int* __restrict__ flag)
{
    int row = blockIdx.x;
    int t = threadIdx.x;
    float v[4];
    if (*flag) {
        float4 f4 = ((const float4*)x)[(size_t)row * 256 + t];
        v[0] = f4.x; v[1] = f4.y; v[2] = f4.z; v[3] = f4.w;
    } else {
        ushort4 uv = ((const ushort4*)x)[(size_t)row * 256 + t];
        v[0] = bf2f(uv.x); v[1] = bf2f(uv.y); v[2] = bf2f(uv.z); v[3] = bf2f(uv.w);
    }
    float s = v[0] + v[1] + v[2] + v[3];
    float q = v[0]*v[0] + v[1]*v[1] + v[2]*v[2] + v[3]*v[3];
    for (int o = 1; o < 64; o <<= 1) { s += __shfl_xor(s, o); q += __shfl_xor(q, o); }
    __shared__ float rs[4], rq[4];
    int wv = t >> 6, ln = t & 63;
    if (ln == 0) { rs[wv] = s; rq[wv] = q; }
    __syncthreads();
    s = rs[0] + rs[1] + rs[2] + rs[3];
    q = rq[0] + rq[1] + rq[2] + rq[3];
    float mu   = s * (1.0f / D_);
    float var  = q * (1.0f / D_) - mu * mu;
    float rstd = rsqrtf(var + 1e-5f);
    u16 o4[4];
    for (int i = 0; i < 4; i++) {
        float f = (v[i] - mu) * rstd * bf2f(g[t*4 + i]) + bf2f(be[t*4 + i]);
        o4[i] = f2bf(f);
    }
    ushort4 ov; ov.x = o4[0]; ov.y = o4[1]; ov.z = o4[2]; ov.w = o4[3];
    *(ushort4*)(xn + (size_t)row * D_ + t * 4) = ov;
}

// ------------- GEMM C = A[8192,1024] . W[1024,1024]^T + bias, *scale -------------
// qkv_mode: z=0 -> Q: bias, l2norm per 64-col head, *QSCALE; z=1 -> K: bias,
// l2norm; z=2 -> V: bias, transposed store Vt[b][h][dk][t]. A wave's 64-col
// span (wn*64..+63) is exactly one head, so the l2norm reduction is 4 shfls
// over the 16-lane l16 group per output row.
__global__ __launch_bounds__(256) void gemm_bt(
    const u16* __restrict__ A,
    const u16* __restrict__ W0, const u16* __restrict__ W1, const u16* __restrict__ W2,
    const u16* __restrict__ bias_all, int bias_idx0,
    u16* __restrict__ C0, u16* __restrict__ C1, u16* __restrict__ C2,
    float scale, const int* __restrict__ flag, int use_flag, int qkv_mode)
{
    const int K = 1024, N = 1024;
    const u16* W; const u16* bias; u16* C;
    if (blockIdx.z == 0)      { W = W0; bias = bias_all + (size_t)bias_idx0 * 1024;       C = C0; }
    else if (blockIdx.z == 1) { W = W1; bias = bias_all + (size_t)(bias_idx0 + 1) * 1024; C = C1; }
    else                      { W = W2; bias = bias_all + (size_t)(bias_idx0 + 2) * 1024; C = C2; }

    __shared__ u16 As[128 * 32];   // no pad: required by global_load_lds layout
    __shared__ u16 Bs[128 * 32];

    int tid  = threadIdx.x;
    int wave = tid >> 6, lane = tid & 63;
    int wm = wave >> 1, wn = wave & 1;
    int quad = lane >> 4, l16 = lane & 15;
    int bm = blockIdx.y * 128, bn = blockIdx.x * 128;

    f32x4 acc[4][4];
    const f32x4 fz = {0.f, 0.f, 0.f, 0.f};
    for (int i = 0; i < 4; i++) for (int j = 0; j < 4; j++) acc[i][j] = fz;

    int srow = lane >> 2;
    int scol = (lane & 3) * 8;
    const u16* gA0 = A + (size_t)(bm + wave * 32 + srow) * K + scol;
    const u16* gB0 = W + (size_t)(bn + wave * 32 + srow) * K + scol;

    for (int k0 = 0; k0 < K; k0 += 32) {
        for (int i = 0; i < 2; i++) {
            __builtin_amdgcn_global_load_lds(
                (const __attribute__((address_space(1))) void*)(gA0 + (size_t)i * 16 * K + k0),
                (__attribute__((address_space(3))) void*)(As + (wave * 32 + i * 16) * 32),
                16, 0, 0);
            __builtin_amdgcn_global_load_lds(
                (const __attribute__((address_space(1))) void*)(gB0 + (size_t)i * 16 * K + k0),
                (__attribute__((address_space(3))) void*)(Bs + (wave * 32 + i * 16) * 32),
                16, 0, 0);
        }
        __syncthreads();
        short8 a[4], b[4];
        for (int i = 0; i < 4; i++)
            a[i] = *(const short8*)(As + (wm * 64 + i * 16 + l16) * 32 + quad * 8);
        for (int j = 0; j < 4; j++)
            b[j] = *(const short8*)(Bs + (wn * 64 + j * 16 + l16) * 32 + quad * 8);
        for (int i = 0; i < 4; i++)
            for (int j = 0; j < 4; j++)
                acc[i][j] = __builtin_amdgcn_mfma_f32_16x16x32_bf16(a[i], b[j], acc[i][j], 0, 0, 0);
        __syncthreads();
    }

    if (qkv_mode) {
        if (blockIdx.z == 2) {
            // Transposed V store: Vt[((b*16+h)*64+d)*2048 + t]
            for (int j = 0; j < 4; j++) {
                int col = bn + wn * 64 + j * 16 + l16;
                int h = col >> 6, d = col & 63;
                float bi = bf2f(bias[col]);
                for (int i = 0; i < 4; i++) {
                    int row0 = bm + wm * 64 + i * 16 + quad * 4;
                    int bq = row0 >> 11, t0 = row0 & 2047;
                    ushort4 pk;
                    pk.x = f2bf(acc[i][j][0] + bi); pk.y = f2bf(acc[i][j][1] + bi);
                    pk.z = f2bf(acc[i][j][2] + bi); pk.w = f2bf(acc[i][j][3] + bi);
                    *(ushort4*)(C + ((size_t)((bq * 16 + h) * 64 + d)) * 2048 + t0) = pk;
                }
            }
        } else {
            // Q/K: bias + per-head l2norm (+QSCALE for Q) fused in epilogue
            float sc2 = (blockIdx.z == 0) ? QSCALE_ : 1.0f;
            float bi[4];
            for (int j = 0; j < 4; j++) bi[j] = bf2f(bias[bn + wn * 64 + j * 16 + l16]);
            for (int i = 0; i < 4; i++) {
                int row0 = bm + wm * 64 + i * 16 + quad * 4;
                for (int r = 0; r < 4; r++) {
                    float v[4]; float s = 0.f;
                    for (int j = 0; j < 4; j++) { v[j] = acc[i][j][r] + bi[j]; s += v[j] * v[j]; }
                    s += __shfl_xor(s, 1); s += __shfl_xor(s, 2);
                    s += __shfl_xor(s, 4); s += __shfl_xor(s, 8);
                    float scl = sc2 / fmaxf(sqrtf(s), 1e-8f);
                    for (int j = 0; j < 4; j++) {
                        int col = bn + wn * 64 + j * 16 + l16;
                        C[(size_t)(row0 + r) * N + col] = f2bf(v[j] * scl);
                    }
                }
            }
        }
        return;
    }

    int f32out = use_flag ? *flag : 0;
    for (int j = 0; j < 4; j++) {
        int col = bn + wn * 64 + j * 16 + l16;
        float bi = bf2f(bias[col]);
        for (int i = 0; i < 4; i++) {
            int row0 = bm + wm * 64 + i * 16 + quad * 4;
            for (int r = 0; r < 4; r++) {
                float o = (acc[i][j][r] + bi) * scale;
                if (f32out) ((float*)C)[(size_t)(row0 + r) * N + col] = o;
                else        C[(size_t)(row0 + r) * N + col] = f2bf(o);
            }
        }
    }
}

// ---------------- Flash-style attention v6 ----------------
// 128 queries/block (32/wave): halves LDS bytes per score vs 64q (the R7
// bottleneck: ~83us of pure LDS-pipe occupancy). Q arrives pre-normalized
// (l2norm+QSCALE in GEMM epilogue) so no in-register norm (R6's spill cause).
// launch_bounds(256,3): VGPR cap ~170 (est ~130). Single-buffer staging with
// register prefetch; 2 barriers/tile. LDS 37.6 KB -> 3 blocks/CU.
__global__ __launch_bounds__(256, 3) void attn_kernel(
    const u16* __restrict__ Q, const u16* __restrict__ Kg,
    const u16* __restrict__ Vt, const u8* __restrict__ nm,
    u16* __restrict__ Oout)
{
    __shared__ u16 Ks[64 * 72];      // [key][dk]
    __shared__ u16 VTs[64 * 72];     // [dk][key]
    __shared__ u16 Ps[128 * 72];     // [query][key] (wave-private row blocks)
    __shared__ __align__(16) float msf[64];  // mask multiplier per key
    __shared__ float l_sh[128];      // per-query denominators

    int tid  = threadIdx.x;
    int wave = tid >> 6, lane = tid & 63;
    int quad = lane >> 4, l16 = lane & 15;
    int q0 = blockIdx.x * 128;
    int b  = blockIdx.y >> 4, h = blockIdx.y & 15;
    const size_t base  = (size_t)b * T_ * D_ + h * DK_;
    const size_t vbase = (size_t)((b * 16 + h) * 64) * T_;

    // Q fragments for two 16-query groups (pre-normalized, pre-scaled)
    short8 qa[2][2];
    for (int g = 0; g < 2; g++) {
        const u16* qrow = Q + base + (size_t)(q0 + wave * 32 + g * 16 + l16) * D_;
        qa[g][0] = *(const short8*)(qrow + quad * 8);
        qa[g][1] = *(const short8*)(qrow + 32 + quad * 8);
    }

    int sr = tid >> 3;                 // 0..31 (p adds 32)
    int sc = (tid & 7) * 8;
    const u8* mrow = nm + b * T_;

    // prologue: stage tile 0
    for (int p = 0; p < 2; p++) {
        int r = sr + p * 32;
        *(short8*)(&Ks[r * 72 + sc])  = *(const short8*)(Kg + base + (size_t)r * D_ + sc);
        *(short8*)(&VTs[r * 72 + sc]) = *(const short8*)(Vt + vbase + (size_t)r * T_ + sc);
    }
    if (tid < 64) msf[tid] = mrow[tid] ? 0.f : 1.f;
    __syncthreads();

    const f32x4 fz = {0.f, 0.f, 0.f, 0.f};
    f32x4 o_acc[2][4];
    for (int g = 0; g < 2; g++) for (int j = 0; j < 4; j++) o_acc[g][j] = fz;
    float rowsum[2] = {0.f, 0.f};

    for (int kt = 0; kt < T_; kt += 64) {
        int ktn = (kt + 64) & (T_ - 1);
        // prefetch next tile into registers (written to LDS after barrier)
        short8 kpre[2], vpre[2];
        for (int p = 0; p < 2; p++) {
            int r = sr + p * 32;
            kpre[p] = *(const short8*)(Kg + base + (size_t)(ktn + r) * D_ + sc);
            vpre[p] = *(const short8*)(Vt + vbase + (size_t)r * T_ + ktn + sc);
        }
        u8 mpre = (tid < 64) ? mrow[ktn + tid] : (u8)0;

        // ---- S^T = K.Q^T -> exp2 -> mask-mul -> packed Ps stores ----
        for (int j = 0; j < 4; j++) {
            short8 kb0 = *(const short8*)(Ks + (j * 16 + l16) * 72 + quad * 8);
            short8 kb1 = *(const short8*)(Ks + (j * 16 + l16) * 72 + 32 + quad * 8);
            f32x4 pm4 = *(const f32x4*)&msf[j * 16 + quad * 4];
            for (int g = 0; g < 2; g++) {
                f32x4 s4 = __builtin_amdgcn_mfma_f32_16x16x32_bf16(kb0, qa[g][0], fz, 0, 0, 0);
                s4       = __builtin_amdgcn_mfma_f32_16x16x32_bf16(kb1, qa[g][1], s4, 0, 0, 0);
                float p0 = __builtin_exp2f(s4[0]) * pm4[0];
                float p1 = __builtin_exp2f(s4[1]) * pm4[1];
                float p2 = __builtin_exp2f(s4[2]) * pm4[2];
                float p3 = __builtin_exp2f(s4[3]) * pm4[3];
                rowsum[g] += (p0 + p1) + (p2 + p3);
                __hip_bfloat162 h01 = __float22bfloat162_rn(float2{p0, p1});
                __hip_bfloat162 h23 = __float22bfloat162_rn(float2{p2, p3});
                uint2 pk;
                __builtin_memcpy(&pk.x, &h01, 4);
                __builtin_memcpy(&pk.y, &h23, 4);
                *(uint2*)(Ps + (wave * 32 + g * 16 + l16) * 72 + j * 16 + quad * 4) = pk;
            }
        }

        // ---- O += P.V (own Ps rows; in-wave DS ordering suffices) ----
        short8 pa0[2], pa1[2];
        for (int g = 0; g < 2; g++) {
            pa0[g] = *(const short8*)(Ps + (wave * 32 + g * 16 + l16) * 72 + quad * 8);
            pa1[g] = *(const short8*)(Ps + (wave * 32 + g * 16 + l16) * 72 + 32 + quad * 8);
        }
        for (int j = 0; j < 4; j++) {
            short8 vb0 = *(const short8*)(VTs + (j * 16 + l16) * 72 + quad * 8);
            short8 vb1 = *(const short8*)(VTs + (j * 16 + l16) * 72 + 32 + quad * 8);
            for (int g = 0; g < 2; g++) {
                o_acc[g][j] = __builtin_amdgcn_mfma_f32_16x16x32_bf16(pa0[g], vb0, o_acc[g][j], 0, 0, 0);
                o_acc[g][j] = __builtin_amdgcn_mfma_f32_16x16x32_bf16(pa1[g], vb1, o_acc[g][j], 0, 0, 0);
            }
        }

        __syncthreads();   // everyone done reading Ks/VTs/msf
        for (int p = 0; p < 2; p++) {
            int r = sr + p * 32;
            *(short8*)(&Ks[r * 72 + sc])  = kpre[p];
            *(short8*)(&VTs[r * 72 + sc]) = vpre[p];
        }
        if (tid < 64) msf[tid] = mpre ? 0.f : 1.f;
        __syncthreads();   // writes visible
    }

    // denominators: reduce across quads (lanes l16, +16, +32, +48)
    for (int g = 0; g < 2; g++) {
        float l = rowsum[g];
        l += __shfl_xor(l, 16);
        l += __shfl_xor(l, 32);
        if (quad == 0) l_sh[wave * 32 + g * 16 + l16] = l;  // own-wave region
    }

    for (int g = 0; g < 2; g++) {
        for (int j = 0; j < 4; j++) {
            for (int r = 0; r < 4; r++) {
                int row = wave * 32 + g * 16 + quad * 4 + r;
                float ld = fmaxf(l_sh[row], 1e-20f);
                float o = o_acc[g][j][r] / ld;
                Oout[base + (size_t)(q0 + row) * D_ + j * 16 + l16] = f2bf(o);
            }
        }
    }
}

extern "C" void kernel_launch(void* const* d_in, const int* in_sizes, int n_in,
                              void* d_out, int out_size, void* d_ws, size_t ws_size,
                              hipStream_t stream)
{
    const void* x    = d_in[0];
    const u8*   mask = (const u8*)d_in[1];
    const void* wq   = d_in[2];
    const void* bq   = d_in[3];
    const void* wk   = d_in[4];
    const void* bk   = d_in[5];
    const void* wv   = d_in[6];
    const void* bv   = d_in[7];
    const void* wo   = d_in[8];
    const void* bo   = d_in[9];
    const void* lng  = d_in[10];
    const void* lnb  = d_in[11];

    const size_t NTOK = (size_t)B_ * T_;          // 8192
    u16* xn  = (u16*)d_ws;                        // 16.8 MB; reused as attention output
    u16* Kb  = xn + NTOK * D_;                    // 16.8 MB
    u16* Vtb = Kb + NTOK * D_;                    // 16.8 MB (transposed layout)
    u16* wqc = Vtb + NTOK * D_;                   // 2 MB each
    u16* wkc = wqc + (size_t)D_ * D_;
    u16* wvc = wkc + (size_t)D_ * D_;
    u16* woc = wvc + (size_t)D_ * D_;
    u16* vecs = woc + (size_t)D_ * D_;            // 6 x 1024: bq,bk,bv,bo,ln_g,ln_b
    u8*  nm  = (u8*)(vecs + 6 * 1024);            // 8 KB canonical mask
    int* flag = (int*)(nm + 8192);                // dtype flag: 1 = fp32 inputs
    u16* Qb  = (u16*)d_out;                       // Q in d_out (dead until final GEMM)

    prep_kernel<<<dim3(1), 256, 0, stream>>>((const u16*)x, mask, bq, bk, bv, bo, lng, lnb,
                                             vecs, nm, flag, B_ * T_);
    convert_w_kernel<<<dim3(1024, 4), 256, 0, stream>>>(wq, wk, wv, wo, wqc, wkc, wvc, woc, flag);
    ln_kernel<<<dim3(NTOK), 256, 0, stream>>>(x, vecs + 4 * 1024, vecs + 5 * 1024, xn, flag);
    gemm_bt<<<dim3(8, 64, 3), 256, 0, stream>>>(xn, wqc, wkc, wvc, vecs, 0, Qb, Kb, Vtb, 1.0f, flag, 0, 1);
    attn_kernel<<<dim3(16, 64), 256, 0, stream>>>(Qb, Kb, Vtb, nm, xn);
    gemm_bt<<<dim3(8, 64, 1), 256, 0, stream>>>(xn, woc, woc, woc, vecs, 3, (u16*)d_out, (u16*)d_out, (u16*)d_out, 0.5f, flag, 1, 0);
}